// Round 8
// baseline (221.097 us; speedup 1.0000x reference)
//
#include <hip/hip_runtime.h>
#include <hip/hip_bf16.h>
#include <stdint.h>

typedef __attribute__((ext_vector_type(8))) short short8;
typedef __attribute__((ext_vector_type(8))) unsigned short u16x8;
typedef __attribute__((ext_vector_type(4))) float f32x4;

__device__ inline unsigned short f2bf(float f) {
  union { float f; unsigned u; } v; v.f = f;
  unsigned r = v.u + 0x7fffu + ((v.u >> 16) & 1u);
  return (unsigned short)(r >> 16);
}

// -------- kernel 1: reconstruct T (1024x1024) as bf16, layout [m][n] ----
__global__ __launch_bounds__(256) void tt_build_T(
    const float* __restrict__ c0, const float* __restrict__ c1,
    const float* __restrict__ c2, const float* __restrict__ c3,
    unsigned short* __restrict__ Tb) {
  __shared__ float L[8192];
  __shared__ float R[8192];
  int t = threadIdx.x;
  for (int i = t; i < 8192; i += 256) {
    int n1 = i & 7, n0 = (i >> 3) & 3, r2 = (i >> 5) & 7, m1 = (i >> 8) & 7, m0 = i >> 11;
    float s = 0.f;
#pragma unroll
    for (int r1 = 0; r1 < 8; ++r1)
      s += c0[(m0 * 8 + r1) * 4 + n0] * c1[(m1 * 8 + r2) * 64 + r1 * 8 + n1];
    L[i] = s;
  }
  for (int i = t; i < 8192; i += 256) {
    int n3 = i & 3, n2 = (i >> 2) & 7, m3 = (i >> 5) & 3, m2 = (i >> 7) & 7, r2 = i >> 10;
    float s = 0.f;
#pragma unroll
    for (int r3 = 0; r3 < 8; ++r3)
      s += c2[(m2 * 8 + r3) * 64 + r2 * 8 + n2] * c3[m3 * 32 + r3 * 4 + n3];
    R[i] = s;
  }
  __syncthreads();
  int base = blockIdx.x * 4096;
  for (int j = 0; j < 16; ++j) {
    int lin = j * 256 + t;
    int g = base + lin;
    int m = g >> 10, n = g & 1023;
    int m0 = m >> 8, m1 = (m >> 5) & 7, m2 = (m >> 2) & 7, m3 = m & 3;
    int n0 = n >> 8, n1 = (n >> 5) & 7, n2 = (n >> 2) & 7, n3 = n & 3;
    float s = 0.f;
#pragma unroll
    for (int r2 = 0; r2 < 8; ++r2)
      s += L[(((m0 * 8 + m1) * 8 + r2) * 4 + n0) * 8 + n1] *
           R[(((r2 * 8 + m2) * 4 + m3) * 8 + n2) * 4 + n3];
    Tb[(size_t)m * 1024 + n] = f2bf(s);
  }
}

// -------- kernel 2: FUSED conv3x3 + GEMM ----
// out[p, m] = relu( sum_c conv(x)[p, c] * T[m, c] + bias[m] )
// Block: 256-pixel M-tile (one batch image, 8 h-rows) x 256-col N-panel. BK=32 ch.
// LDS (128 KiB):
//   x ring-2:  2 x 40960 B  ([10 rows][32 w][8 x 16B chunks], chunk pos = src ^ ((w&3)<<1))
//   A:         16384 B      ([128 lines][8 x 16B slots], slot = src ^ (line&7)) row-pair swz
//   B ring-2:  2 x 16384 B  (same line swizzle, 256 rows x 32 k bf16)
__device__ inline void stage16(const void* g, void* l) {
  __builtin_amdgcn_global_load_lds(
      (const __attribute__((address_space(1))) void*)g,
      (__attribute__((address_space(3))) void*)l, 16, 0, 0);
}

#define XB0 0
#define XB1 40960
#define AB  81920
#define BB0 98304
#define BB1 114688

__global__ __launch_bounds__(512, 2) void tt_fused(
    const float* __restrict__ x, const float* __restrict__ filt,
    const unsigned short* __restrict__ Bt, const float* __restrict__ bias,
    const float* __restrict__ zp, float* __restrict__ C) {
  __shared__ __align__(16) char lds[131072];
  const int tid = threadIdx.x;
  const int lane = tid & 63, wave = tid >> 6;
  const int wr = wave >> 2, wc = wave & 3;      // 2M x 4N waves; per-wave 128x64
  const int lr = lane & 15, kc = lane >> 4;

  // XCD swizzle: 256 blocks; each XCD = 32 contiguous M-tiles within one N-panel.
  int bid = blockIdx.x;
  int lin = (bid & 7) * 32 + (bid >> 3);
  int np = lin >> 6, mt = lin & 63;
  int b = mt >> 2, h0 = (mt & 3) * 8;
  int brow = mt * 256, bcol = np * 256;

  // ---- x staging descriptors: 2560 chunks of 16B; thread stages 5 ----
  const float* xsrc[5];
  int xstep[5], xdst[5];
#pragma unroll
  for (int i = 0; i < 5; ++i) {
    int q = tid + 512 * i;
    int r = q >> 8, w = (q >> 3) & 31;
    int c4 = (q & 7) ^ ((w & 3) << 1);
    int gh = h0 - 1 + r;
    bool ok = (unsigned)gh < 32u;
    xsrc[i] = ok ? x + (((size_t)(b * 32 + gh) * 32 + w) << 10) + c4 * 4
                 : zp + ((q & 2047) << 2);
    xstep[i] = ok ? 32 : 0;
    xdst[i] = q * 16;
  }
  // ---- B staging descriptors: 1024 chunks; thread stages 2 (pre-swizzled src) ----
  const unsigned short* bsrc[2];
  int bdst[2];
#pragma unroll
  for (int j = 0; j < 2; ++j) {
    int q = tid + 512 * j;
    int li = q >> 3, sl = (q & 7) ^ (li & 7);
    int row = 2 * li + (sl >> 2), ck = sl & 3;
    bsrc[j] = Bt + (size_t)(bcol + row) * 1024 + ck * 8;
    bdst[j] = q * 16;
  }

  // ---- conv thread mapping: 2 h-adjacent pixels x 8 ch ----
  const int cg = tid & 3, cw = (tid >> 2) & 31, hp = tid >> 7;  // hp 0..3
  const int lr0 = 2 * hp;
  int wo0, wo1;
  {
    int pp = lr0 * 32 + cw;
    int li = pp >> 1, sl = (pp & 1) * 4 + cg;
    wo0 = AB + li * 128 + (sl ^ (li & 7)) * 16;
    pp += 32;
    li = pp >> 1; sl = (pp & 1) * 4 + cg;
    wo1 = AB + li * 128 + (sl ^ (li & 7)) * 16;
  }
  float F[9];
#pragma unroll
  for (int i = 0; i < 9; ++i) F[i] = filt[i];

  // ---- MFMA fragment offsets (bytes, swizzled) ----
  int offA[8], offB[4];
#pragma unroll
  for (int m = 0; m < 8; ++m) {
    int row = wr * 128 + m * 16 + lr;
    int li = row >> 1, sl = (row & 1) * 4 + kc;
    offA[m] = AB + li * 128 + (sl ^ (li & 7)) * 16;
  }
#pragma unroll
  for (int n = 0; n < 4; ++n) {
    int row = wc * 64 + n * 16 + lr;
    int li = row >> 1, sl = (row & 1) * 4 + kc;
    offB[n] = li * 128 + (sl ^ (li & 7)) * 16;
  }

  f32x4 acc[8][4] = {};
  const float4 z4 = {0.f, 0.f, 0.f, 0.f};

#define STAGE(XOFF, BOFF, T) { \
    _Pragma("unroll") for (int i = 0; i < 5; ++i) \
      stage16(xsrc[i] + (size_t)(T) * xstep[i], lds + (XOFF) + xdst[i]); \
    _Pragma("unroll") for (int j = 0; j < 2; ++j) \
      stage16(bsrc[j] + (T) * 32, lds + (BOFF) + bdst[j]); }

#define CONV(XOFF) { \
    float4 s0a = z4, s0b = z4, s1a = z4, s1b = z4; \
    _Pragma("unroll") for (int rr = 0; rr < 4; ++rr) { \
      _Pragma("unroll") for (int dw = 0; dw < 3; ++dw) { \
        int wq = cw + dw - 1; \
        float4 va = z4, vb = z4; \
        if ((unsigned)wq < 32u) { \
          const char* p = lds + (XOFF) + (lr0 + rr) * 4096 + wq * 128 + \
                          (((2 * cg) ^ ((wq & 3) << 1)) * 16); \
          va = *reinterpret_cast<const float4*>(p); \
          vb = *reinterpret_cast<const float4*>(p + 16); \
        } \
        if (rr < 3) { float f = F[rr * 3 + dw]; \
          s0a.x += f * va.x; s0a.y += f * va.y; s0a.z += f * va.z; s0a.w += f * va.w; \
          s0b.x += f * vb.x; s0b.y += f * vb.y; s0b.z += f * vb.z; s0b.w += f * vb.w; } \
        if (rr > 0) { float f = F[(rr - 1) * 3 + dw]; \
          s1a.x += f * va.x; s1a.y += f * va.y; s1a.z += f * va.z; s1a.w += f * va.w; \
          s1b.x += f * vb.x; s1b.y += f * vb.y; s1b.z += f * vb.z; s1b.w += f * vb.w; } \
      } \
    } \
    u16x8 o; \
    o[0] = f2bf(s0a.x); o[1] = f2bf(s0a.y); o[2] = f2bf(s0a.z); o[3] = f2bf(s0a.w); \
    o[4] = f2bf(s0b.x); o[5] = f2bf(s0b.y); o[6] = f2bf(s0b.z); o[7] = f2bf(s0b.w); \
    *reinterpret_cast<u16x8*>(lds + wo0) = o; \
    o[0] = f2bf(s1a.x); o[1] = f2bf(s1a.y); o[2] = f2bf(s1a.z); o[3] = f2bf(s1a.w); \
    o[4] = f2bf(s1b.x); o[5] = f2bf(s1b.y); o[6] = f2bf(s1b.z); o[7] = f2bf(s1b.w); \
    *reinterpret_cast<u16x8*>(lds + wo1) = o; }

#define MFMA_PH(BOFF) { \
    short8 af[8], bfr[4]; \
    _Pragma("unroll") for (int m = 0; m < 8; ++m) \
      af[m] = *reinterpret_cast<const short8*>(lds + offA[m]); \
    _Pragma("unroll") for (int n = 0; n < 4; ++n) \
      bfr[n] = *reinterpret_cast<const short8*>(lds + (BOFF) + offB[n]); \
    _Pragma("unroll") for (int m = 0; m < 8; ++m) \
      _Pragma("unroll") for (int n = 0; n < 4; ++n) \
        acc[m][n] = __builtin_amdgcn_mfma_f32_16x16x32_bf16(bfr[n], af[m], acc[m][n], 0, 0, 0); }

  // TILE: drain stage(t) [counted domain empty besides it]; b1; prefetch t+1;
  // conv(t) -> A; lgkm-fence + b2; open MFMA region.
#define TILE(T, XR, BR, XS, BS) { \
    asm volatile("s_waitcnt vmcnt(0)" ::: "memory"); \
    __builtin_amdgcn_s_barrier(); \
    asm volatile("" ::: "memory"); \
    if ((T) + 1 < 32) STAGE(XS, BS, (T) + 1); \
    CONV(XR); \
    asm volatile("s_waitcnt lgkmcnt(0)" ::: "memory"); \
    __builtin_amdgcn_s_barrier(); \
    MFMA_PH(BR); }

  STAGE(XB0, BB0, 0);
  for (int t = 0; t < 32; t += 2) {
    TILE(t, XB0, BB0, XB1, BB1)
    TILE(t + 1, XB1, BB1, XB0, BB0)
  }

#undef TILE
#undef MFMA_PH
#undef CONV
#undef STAGE

  // epilogue: bias + relu, f32x4 stores (acc j-dim col-contiguous via operand swap)
#pragma unroll
  for (int n = 0; n < 4; ++n) {
    int col = bcol + wc * 64 + n * 16 + kc * 4;
    float4 bv = *reinterpret_cast<const float4*>(&bias[col]);
#pragma unroll
    for (int m = 0; m < 8; ++m) {
      int row = brow + wr * 128 + m * 16 + lr;
      f32x4 v = acc[m][n];
      float4 o;
      o.x = v[0] + bv.x; o.y = v[1] + bv.y; o.z = v[2] + bv.z; o.w = v[3] + bv.w;
      o.x = o.x > 0.f ? o.x : 0.f;
      o.y = o.y > 0.f ? o.y : 0.f;
      o.z = o.z > 0.f ? o.z : 0.f;
      o.w = o.w > 0.f ? o.w : 0.f;
      *reinterpret_cast<float4*>(&C[(size_t)row * 1024 + col]) = o;
    }
  }
}

extern "C" void kernel_launch(void* const* d_in, const int* in_sizes, int n_in,
                              void* d_out, int out_size, void* d_ws, size_t ws_size,
                              hipStream_t stream) {
  const float* x = (const float*)d_in[0];
  const float* filt = (const float*)d_in[1];
  const float* c0 = (const float*)d_in[2];
  const float* c1 = (const float*)d_in[3];
  const float* c2 = (const float*)d_in[4];
  const float* c3 = (const float*)d_in[5];
  const float* bias = (const float*)d_in[6];
  float* out = (float*)d_out;

  unsigned short* Tb = (unsigned short*)d_ws;               // 2 MB
  float* zp = (float*)((char*)d_ws + (2u << 20));           // 64 KB zero page

  hipMemsetAsync(zp, 0, 65536, stream);
  tt_build_T<<<256, 256, 0, stream>>>(c0, c1, c2, c3, Tb);
  tt_fused<<<256, 512, 0, stream>>>(x, filt, Tb, bias, zp, out);
}

// Round 10
// 85.381 us; speedup vs baseline: 2.5895x; 2.5895x over previous
//
#include <hip/hip_runtime.h>
#include <hip/hip_bf16.h>
#include <stdint.h>

typedef __attribute__((ext_vector_type(8))) short short8;
typedef __attribute__((ext_vector_type(4))) float f32x4;

__device__ inline unsigned short f2bf(float f) {
  union { float f; unsigned u; } v; v.f = f;
  unsigned r = v.u + 0x7fffu + ((v.u >> 16) & 1u);
  return (unsigned short)(r >> 16);
}

// -------- kernel 1: reconstruct T (1024x1024) as bf16, layout [m][n] ----
__global__ __launch_bounds__(256) void tt_build_T(
    const float* __restrict__ c0, const float* __restrict__ c1,
    const float* __restrict__ c2, const float* __restrict__ c3,
    unsigned short* __restrict__ Tb) {
  __shared__ float L[8192];
  __shared__ float R[8192];
  int t = threadIdx.x;
  for (int i = t; i < 8192; i += 256) {
    int n1 = i & 7, n0 = (i >> 3) & 3, r2 = (i >> 5) & 7, m1 = (i >> 8) & 7, m0 = i >> 11;
    float s = 0.f;
#pragma unroll
    for (int r1 = 0; r1 < 8; ++r1)
      s += c0[(m0 * 8 + r1) * 4 + n0] * c1[(m1 * 8 + r2) * 64 + r1 * 8 + n1];
    L[i] = s;
  }
  for (int i = t; i < 8192; i += 256) {
    int n3 = i & 3, n2 = (i >> 2) & 7, m3 = (i >> 5) & 3, m2 = (i >> 7) & 7, r2 = i >> 10;
    float s = 0.f;
#pragma unroll
    for (int r3 = 0; r3 < 8; ++r3)
      s += c2[(m2 * 8 + r3) * 64 + r2 * 8 + n2] * c3[m3 * 32 + r3 * 4 + n3];
    R[i] = s;
  }
  __syncthreads();
  int base = blockIdx.x * 4096;
  for (int j = 0; j < 16; ++j) {
    int lin = j * 256 + t;
    int g = base + lin;
    int m = g >> 10, n = g & 1023;
    int m0 = m >> 8, m1 = (m >> 5) & 7, m2 = (m >> 2) & 7, m3 = m & 3;
    int n0 = n >> 8, n1 = (n >> 5) & 7, n2 = (n >> 2) & 7, n3 = n & 3;
    float s = 0.f;
#pragma unroll
    for (int r2 = 0; r2 < 8; ++r2)
      s += L[(((m0 * 8 + m1) * 8 + r2) * 4 + n0) * 8 + n1] *
           R[(((r2 * 8 + m2) * 4 + m3) * 8 + n2) * 4 + n3];
    Tb[(size_t)m * 1024 + n] = f2bf(s);
  }
}

// -------- kernel 2: depthwise 3x3 SAME conv with LDS strip staging ------
__global__ __launch_bounds__(256) void tt_conv3x3_lds(
    const float* __restrict__ x, const float* __restrict__ filt,
    unsigned short* __restrict__ D) {
  __shared__ float xs[10][32][32];
  int bid = blockIdx.x;                 // 2048 = 16b * 4strip * 32cg
  int cg = bid & 31, strip = (bid >> 5) & 3, b = bid >> 7;
  int h0 = strip * 8;
  int tid = threadIdx.x;
  float4 z4; z4.x = z4.y = z4.z = z4.w = 0.f;
#pragma unroll
  for (int i = 0; i < 10; ++i) {
    int j = tid + 256 * i;
    int row = j >> 8, w = (j >> 3) & 31, c4 = j & 7;
    int gh = h0 - 1 + row;
    float4 v = z4;
    if ((unsigned)gh < 32u)
      v = *reinterpret_cast<const float4*>(x + ((size_t)((b * 32 + gh) * 32 + w)) * 1024 + cg * 32 + c4 * 4);
    *reinterpret_cast<float4*>(&xs[row][w][c4 * 4]) = v;
  }
  float F[9];
#pragma unroll
  for (int i = 0; i < 9; ++i) F[i] = filt[i];
  __syncthreads();

  int c4 = tid & 7, w = tid >> 3;
#define LD3(r, d0, d1, d2) { \
    d1 = *reinterpret_cast<const float4*>(&xs[r][w][c4 * 4]); \
    d0 = (w > 0)  ? *reinterpret_cast<const float4*>(&xs[r][w - 1][c4 * 4]) : z4; \
    d2 = (w < 31) ? *reinterpret_cast<const float4*>(&xs[r][w + 1][c4 * 4]) : z4; }
#define ACC4(a, f, v) { a.x += (f) * v.x; a.y += (f) * v.y; a.z += (f) * v.z; a.w += (f) * v.w; }
  float4 a00, a01, a02, a10, a11, a12, a20, a21, a22;
  LD3(0, a00, a01, a02);
  LD3(1, a10, a11, a12);
#pragma unroll
  for (int h = 0; h < 8; ++h) {
    LD3(h + 2, a20, a21, a22);
    float4 s = z4;
    ACC4(s, F[0], a00); ACC4(s, F[1], a01); ACC4(s, F[2], a02);
    ACC4(s, F[3], a10); ACC4(s, F[4], a11); ACC4(s, F[5], a12);
    ACC4(s, F[6], a20); ACC4(s, F[7], a21); ACC4(s, F[8], a22);
    ushort4 o;
    o.x = f2bf(s.x); o.y = f2bf(s.y); o.z = f2bf(s.z); o.w = f2bf(s.w);
    *reinterpret_cast<ushort4*>(&D[((size_t)(b * 1024 + (h0 + h) * 32 + w)) * 1024 + cg * 32 + c4 * 4]) = o;
    a00 = a10; a01 = a11; a02 = a12;
    a10 = a20; a11 = a21; a12 = a22;
  }
#undef LD3
#undef ACC4
}

// -------- kernel 3: 8-phase 256x256 GEMM, BK=64 — TAIL-vmcnt (race-fixed) ----
// C[p,m] = relu( sum_k D[p,k]*Tb[m,k] + bias[m] ), M=16384, N=1024, K=1024.
// LDS: Ah/Bh [2 dbuf][2 khalf][256x32] bf16 = 128 KiB total.
// Phase p reads data staged exactly 6 phases earlier (2 loads/thread/phase):
//   reads@ph0: Ah/Bh[0][0]  <- staged prev-iter ph2,ph3
//   reads@ph2: Ah/Bh[0][1]  <- staged prev-iter ph4,ph5
//   reads@ph4: Ah/Bh[1][0]  <- staged prev-iter ph6,ph7
//   reads@ph6: Ah/Bh[1][1]  <- staged THIS-iter ph0,ph1
// Residency: counted vmcnt(8) at TAILS of ph1/ph3/ph5/ph7 (after MFMA, before
// closing barrier) retires exactly the pair read one phase later; barrier
// orders it across waves. Prologue: 12 loads + vmcnt(8) + barrier. Peeled last
// iter tails: 8 / 4 / 0 (fewer stages in flight). Never a mid-loop full drain.
// Slot-overwrite safety: each ST_ targets a slot last READ >=1 closing barrier
// earlier (reads complete before their consuming MFMA via compiler lgkm waits).
// Swizzle: row-pair 128B lines, slot' = slot ^ (line&7); pre-swizzled GLOBAL
// source, linear LDS dest (gload_lds rule #21).
__device__ inline void stage16(const unsigned short* g, unsigned short* l) {
  __builtin_amdgcn_global_load_lds(
      (const __attribute__((address_space(1))) void*)g,
      (__attribute__((address_space(3))) void*)l, 16, 0, 0);
}

__global__ __launch_bounds__(512, 2) void tt_gemm_8t(
    const unsigned short* __restrict__ A,   // [16384, 1024] bf16
    const unsigned short* __restrict__ Bt,  // [1024, 1024] bf16
    const float* __restrict__ bias,
    float* __restrict__ C) {
  __shared__ __align__(16) unsigned short Ah[2][2][8192];
  __shared__ __align__(16) unsigned short Bh[2][2][8192];
  const int tid = threadIdx.x;
  const int lane = tid & 63, wave = tid >> 6;
  const int wr = wave >> 2, wc = wave & 3;      // 2M x 4N waves; per-wave 128x64
  const int lr = lane & 15, kc = lane >> 4;

  // XCD-bijective swizzle (256 blocks, 8 XCDs)
  int lin = blockIdx.x + blockIdx.y * 64;
  int Lg = ((lin & 7) << 5) | (lin >> 3);
  int brow = (Lg & 63) * 256;
  int bcol = (Lg >> 6) * 256;

  // staging: half-tile = 1024 x 16B chunks; thread stages q0=tid, q1=tid+512
  int row0, k0, row1, k1;
  { int q = tid;       int li = q >> 3, c = (q & 7) ^ (li & 7); row0 = 2 * li + (c >> 2); k0 = (c & 3) * 8; }
  { int q = tid + 512; int li = q >> 3, c = (q & 7) ^ (li & 7); row1 = 2 * li + (c >> 2); k1 = (c & 3) * 8; }
  const unsigned short* pa0 = A + (size_t)(brow + row0) * 1024 + k0;
  const unsigned short* pa1 = A + (size_t)(brow + row1) * 1024 + k1;
  const unsigned short* pb0 = Bt + (size_t)(bcol + row0) * 1024 + k0;
  const unsigned short* pb1 = Bt + (size_t)(bcol + row1) * 1024 + k1;
  const int la0 = tid * 8, la1 = (tid + 512) * 8;

  // swizzled ds_read offsets (shorts within one 8192-short slot)
  int offA[8], offB[4];
#pragma unroll
  for (int m = 0; m < 8; ++m) {
    int row = wr * 128 + m * 16 + lr;
    int li = row >> 1, sl = (row & 1) * 4 + kc;
    offA[m] = (li * 8 + (sl ^ (li & 7))) * 8;
  }
#pragma unroll
  for (int n = 0; n < 4; ++n) {
    int row = wc * 64 + n * 16 + lr;
    int li = row >> 1, sl = (row & 1) * 4 + kc;
    offB[n] = (li * 8 + (sl ^ (li & 7))) * 8;
  }

  f32x4 acc[8][4] = {};
  short8 bfr[4];

#define ST_A(D, KH, KT) do { \
    stage16(pa0 + (KT) * 64 + (KH) * 32, &Ah[D][KH][la0]); \
    stage16(pa1 + (KT) * 64 + (KH) * 32, &Ah[D][KH][la1]); } while (0)
#define ST_B(D, KH, KT) do { \
    stage16(pb0 + (KT) * 64 + (KH) * 32, &Bh[D][KH][la0]); \
    stage16(pb1 + (KT) * 64 + (KH) * 32, &Bh[D][KH][la1]); } while (0)
#define VM8 asm volatile("s_waitcnt vmcnt(8)" ::: "memory")
#define VM4 asm volatile("s_waitcnt vmcnt(4)" ::: "memory")
#define VM0 asm volatile("s_waitcnt vmcnt(0)" ::: "memory")
#define NOPV (void)0

#define PH(D, KK, MH, LOADB, STG, TV) { \
    if (LOADB) { \
      _Pragma("unroll") for (int n = 0; n < 4; ++n) \
        bfr[n] = *reinterpret_cast<const short8*>(&Bh[D][KK][offB[n]]); \
    } \
    short8 af[4]; \
    _Pragma("unroll") for (int m = 0; m < 4; ++m) \
      af[m] = *reinterpret_cast<const short8*>(&Ah[D][KK][offA[(MH) * 4 + m]]); \
    STG; \
    __builtin_amdgcn_s_barrier(); \
    asm volatile("s_waitcnt lgkmcnt(0)" ::: "memory"); \
    __builtin_amdgcn_s_setprio(1); \
    _Pragma("unroll") for (int m = 0; m < 4; ++m) \
      _Pragma("unroll") for (int n = 0; n < 4; ++n) \
        acc[(MH) * 4 + m][n] = __builtin_amdgcn_mfma_f32_16x16x32_bf16(bfr[n], af[m], acc[(MH) * 4 + m][n], 0, 0, 0); \
    __builtin_amdgcn_s_setprio(0); \
    TV; \
    __builtin_amdgcn_s_barrier(); }

  // prologue: 6 half-tiles (12 loads); retire the first 2 (tile0 k-half0) and
  // barrier so ph0's reads are globally resident.
  ST_A(0, 0, 0); ST_B(0, 0, 0);
  ST_A(0, 1, 0); ST_B(0, 1, 0);
  ST_A(1, 0, 1); ST_B(1, 0, 1);
  VM8;
  __builtin_amdgcn_s_barrier();

  for (int i = 0; i < 7; ++i) {
    int t = 2 * i;
    PH(0, 0, 0, 1, ST_A(1, 1, t + 1), NOPV)
    PH(0, 0, 1, 0, ST_B(1, 1, t + 1), VM8)
    PH(0, 1, 0, 1, ST_A(0, 0, t + 2), NOPV)
    PH(0, 1, 1, 0, ST_B(0, 0, t + 2), VM8)
    PH(1, 0, 0, 1, ST_A(0, 1, t + 2), NOPV)
    PH(1, 0, 1, 0, ST_B(0, 1, t + 2), VM8)
    PH(1, 1, 0, 1, ST_A(1, 0, t + 3), NOPV)
    PH(1, 1, 1, 0, ST_B(1, 0, t + 3), VM8)
  }
  // peeled last iter (tiles 14,15): only ph0/ph1 stage (tile15 k-half1).
  PH(0, 0, 0, 1, ST_A(1, 1, 15), NOPV)
  PH(0, 0, 1, 0, ST_B(1, 1, 15), VM8)
  PH(0, 1, 0, 1, NOPV, NOPV)
  PH(0, 1, 1, 0, NOPV, VM4)
  PH(1, 0, 0, 1, NOPV, NOPV)
  PH(1, 0, 1, 0, NOPV, VM0)
  PH(1, 1, 0, 1, NOPV, NOPV)
  PH(1, 1, 1, 0, NOPV, NOPV)

#undef PH
#undef ST_A
#undef ST_B
#undef VM8
#undef VM4
#undef VM0
#undef NOPV

  // epilogue: bias + relu, f32x4 stores (acc j-dim col-contiguous via operand swap)
#pragma unroll
  for (int n = 0; n < 4; ++n) {
    int col = bcol + wc * 64 + n * 16 + kc * 4;
    float4 bv = *reinterpret_cast<const float4*>(&bias[col]);
#pragma unroll
    for (int m = 0; m < 8; ++m) {
      int row = brow + wr * 128 + m * 16 + lr;
      f32x4 v = acc[m][n];
      float4 o;
      o.x = v[0] + bv.x; o.y = v[1] + bv.y; o.z = v[2] + bv.z; o.w = v[3] + bv.w;
      o.x = o.x > 0.f ? o.x : 0.f;
      o.y = o.y > 0.f ? o.y : 0.f;
      o.z = o.z > 0.f ? o.z : 0.f;
      o.w = o.w > 0.f ? o.w : 0.f;
      *reinterpret_cast<float4*>(&C[(size_t)row * 1024 + col]) = o;
    }
  }
}

extern "C" void kernel_launch(void* const* d_in, const int* in_sizes, int n_in,
                              void* d_out, int out_size, void* d_ws, size_t ws_size,
                              hipStream_t stream) {
  const float* x = (const float*)d_in[0];
  const float* filt = (const float*)d_in[1];
  const float* c0 = (const float*)d_in[2];
  const float* c1 = (const float*)d_in[3];
  const float* c2 = (const float*)d_in[4];
  const float* c3 = (const float*)d_in[5];
  const float* bias = (const float*)d_in[6];
  float* out = (float*)d_out;

  unsigned short* Tb = (unsigned short*)d_ws;        // 2 MB
  unsigned short* D = Tb + (size_t)1024 * 1024;      // 32 MB

  tt_build_T<<<256, 256, 0, stream>>>(c0, c1, c2, c3, Tb);
  tt_conv3x3_lds<<<2048, 256, 0, stream>>>(x, filt, D);
  dim3 grid(64, 4);
  tt_gemm_8t<<<grid, 512, 0, stream>>>(D, Tb, bias, out);
}

// Round 11
// 74.806 us; speedup vs baseline: 2.9556x; 1.1414x over previous
//
#include <hip/hip_runtime.h>
#include <hip/hip_bf16.h>
#include <stdint.h>

typedef __attribute__((ext_vector_type(8))) short short8;
typedef __attribute__((ext_vector_type(4))) float f32x4;

__device__ inline unsigned short f2bf(float f) {
  union { float f; unsigned u; } v; v.f = f;
  unsigned r = v.u + 0x7fffu + ((v.u >> 16) & 1u);
  return (unsigned short)(r >> 16);
}
__device__ inline float bf2f(unsigned short u) {
  union { unsigned u; float f; } v; v.u = ((unsigned)u) << 16; return v.f;
}

// -------- kernel 1: MERGED prep: blocks 0..255 build T (bf16), 256..2303 conv ----
// buildT: L[m0,m1,r2,n0,n1], R[r2,m2,m3,n2,n3] stored bf16 in 32 KB LDS
// (bf16 L/R adds ~0.5% rel err on T -> negligible vs bf16 GEMM inputs).
// conv: depthwise 3x3 SAME, LDS strip staging (40 KB), unchanged from R4.
__global__ __launch_bounds__(256) void tt_prep(
    const float* __restrict__ x, const float* __restrict__ filt,
    const float* __restrict__ c0, const float* __restrict__ c1,
    const float* __restrict__ c2, const float* __restrict__ c3,
    unsigned short* __restrict__ Tb, unsigned short* __restrict__ D) {
  __shared__ __align__(16) char smem[40960];
  const int tid = threadIdx.x;
  const int bid = blockIdx.x;

  if (bid < 256) {
    // ---- build T ----
    unsigned short* Lb = (unsigned short*)smem;          // 8192 bf16
    unsigned short* Rb = (unsigned short*)(smem + 16384);
    for (int i = tid; i < 8192; i += 256) {
      int n1 = i & 7, n0 = (i >> 3) & 3, r2 = (i >> 5) & 7, m1 = (i >> 8) & 7, m0 = i >> 11;
      float s = 0.f;
#pragma unroll
      for (int r1 = 0; r1 < 8; ++r1)
        s += c0[(m0 * 8 + r1) * 4 + n0] * c1[(m1 * 8 + r2) * 64 + r1 * 8 + n1];
      Lb[i] = f2bf(s);
    }
    for (int i = tid; i < 8192; i += 256) {
      int n3 = i & 3, n2 = (i >> 2) & 7, m3 = (i >> 5) & 3, m2 = (i >> 7) & 7, r2 = i >> 10;
      float s = 0.f;
#pragma unroll
      for (int r3 = 0; r3 < 8; ++r3)
        s += c2[(m2 * 8 + r3) * 64 + r2 * 8 + n2] * c3[m3 * 32 + r3 * 4 + n3];
      Rb[i] = f2bf(s);
    }
    __syncthreads();
    int base = bid * 4096;
    for (int j = 0; j < 16; ++j) {
      int g = base + j * 256 + tid;
      int m = g >> 10, n = g & 1023;
      int m0 = m >> 8, m1 = (m >> 5) & 7, m2 = (m >> 2) & 7, m3 = m & 3;
      int n0 = n >> 8, n1 = (n >> 5) & 7, n2 = (n >> 2) & 7, n3 = n & 3;
      float s = 0.f;
#pragma unroll
      for (int r2 = 0; r2 < 8; ++r2)
        s += bf2f(Lb[(((m0 * 8 + m1) * 8 + r2) * 4 + n0) * 8 + n1]) *
             bf2f(Rb[(((r2 * 8 + m2) * 4 + m3) * 8 + n2) * 4 + n3]);
      Tb[(size_t)m * 1024 + n] = f2bf(s);
    }
    return;
  }

  // ---- conv ----
  float (*xs)[32][32] = (float(*)[32][32])smem;  // [10][32][32]
  int cb = bid - 256;                 // 2048 = 16b * 4strip * 32cg
  int cg = cb & 31, strip = (cb >> 5) & 3, b = cb >> 7;
  int h0 = strip * 8;
  float4 z4; z4.x = z4.y = z4.z = z4.w = 0.f;
#pragma unroll
  for (int i = 0; i < 10; ++i) {
    int j = tid + 256 * i;
    int row = j >> 8, w = (j >> 3) & 31, c4 = j & 7;
    int gh = h0 - 1 + row;
    float4 v = z4;
    if ((unsigned)gh < 32u)
      v = *reinterpret_cast<const float4*>(x + ((size_t)((b * 32 + gh) * 32 + w)) * 1024 + cg * 32 + c4 * 4);
    *reinterpret_cast<float4*>(&xs[row][w][c4 * 4]) = v;
  }
  float F[9];
#pragma unroll
  for (int i = 0; i < 9; ++i) F[i] = filt[i];
  __syncthreads();

  int c4 = tid & 7, w = tid >> 3;
#define LD3(r, d0, d1, d2) { \
    d1 = *reinterpret_cast<const float4*>(&xs[r][w][c4 * 4]); \
    d0 = (w > 0)  ? *reinterpret_cast<const float4*>(&xs[r][w - 1][c4 * 4]) : z4; \
    d2 = (w < 31) ? *reinterpret_cast<const float4*>(&xs[r][w + 1][c4 * 4]) : z4; }
#define ACC4(a, f, v) { a.x += (f) * v.x; a.y += (f) * v.y; a.z += (f) * v.z; a.w += (f) * v.w; }
  float4 a00, a01, a02, a10, a11, a12, a20, a21, a22;
  LD3(0, a00, a01, a02);
  LD3(1, a10, a11, a12);
#pragma unroll
  for (int h = 0; h < 8; ++h) {
    LD3(h + 2, a20, a21, a22);
    float4 s = z4;
    ACC4(s, F[0], a00); ACC4(s, F[1], a01); ACC4(s, F[2], a02);
    ACC4(s, F[3], a10); ACC4(s, F[4], a11); ACC4(s, F[5], a12);
    ACC4(s, F[6], a20); ACC4(s, F[7], a21); ACC4(s, F[8], a22);
    ushort4 o;
    o.x = f2bf(s.x); o.y = f2bf(s.y); o.z = f2bf(s.z); o.w = f2bf(s.w);
    *reinterpret_cast<ushort4*>(&D[((size_t)(b * 1024 + (h0 + h) * 32 + w)) * 1024 + cg * 32 + c4 * 4]) = o;
    a00 = a10; a01 = a11; a02 = a12;
    a10 = a20; a11 = a21; a12 = a22;
  }
#undef LD3
#undef ACC4
}

// -------- kernel 2: 128x512 GEMM, BK=32, ring-3, R4-p3 schedule, XCD-panel-pinned ----
// C[p,m] = relu( sum_k D[p,k]*Tb[m,k] + bias[m] ), M=16384, N=1024, K=1024.
// Each XCD's 32 blocks share ONE 1MB B-panel (L2-resident); A re-read drops to 2x.
// Swizzle: rows paired into 128B lines (8 x 16B slots); slot' = slot ^ (line&7).
// Staging pre-swizzles the GLOBAL source; LDS dest stays linear (gload_lds rule).
// 5 loads/thread/tile (1A + 4B) split 2B | 1A+2B; ring-3 stage t+2; counted
// vmcnt: main 7 (= t+1's 5 + t+2's first 2 still in flight), tails 5 / 0.
__device__ inline void stage16(const unsigned short* g, unsigned short* l) {
  __builtin_amdgcn_global_load_lds(
      (const __attribute__((address_space(1))) void*)g,
      (__attribute__((address_space(3))) void*)l, 16, 0, 0);
}

__global__ __launch_bounds__(512, 2) void tt_gemm_n5(
    const unsigned short* __restrict__ A,   // [16384, 1024] bf16
    const unsigned short* __restrict__ Bt,  // [1024, 1024] bf16
    const float* __restrict__ bias,
    float* __restrict__ C) {
  // ring slot: [A: 0..4096 shorts (128x32)][B: 4096..20480 (512x32)] = 40 KB; x3 = 120 KB
  __shared__ unsigned short lds[3][20480];
  const int tid = threadIdx.x;
  const int lane = tid & 63, wave = tid >> 6;
  const int wr = wave >> 2, wc = wave & 3;      // 2M x 4N waves; per-wave 64x128
  const int lr = lane & 15, kc = lane >> 4;

  // panel pinning: XCDs 0-3 -> panel 0, XCDs 4-7 -> panel 1 (bid%8 ~ XCD heuristic)
  int bid = blockIdx.x;
  int panel = (bid & 7) >> 2;
  int mtile = ((bid >> 3) << 2) | (bid & 3);    // 0..127, bijective with panel
  int brow = mtile * 128, bcol = panel * 512;

  // staging descriptors (pre-swizzled source)
  int rowA, kA;
  { int q = tid; int li = q >> 3, sl = (q & 7) ^ (li & 7); rowA = 2 * li + (sl >> 2); kA = (sl & 3) * 8; }
  const unsigned short* srcA = A + (size_t)(brow + rowA) * 1024 + kA;
  const int la = tid * 8;
  const unsigned short* srcB[4];
  int lb[4];
#pragma unroll
  for (int j = 0; j < 4; ++j) {
    int q = tid + 512 * j;
    int li = q >> 3, sl = (q & 7) ^ (li & 7);
    int row = 2 * li + (sl >> 2), k = (sl & 3) * 8;
    srcB[j] = Bt + (size_t)(bcol + row) * 1024 + k;
    lb[j] = 4096 + q * 8;
  }

  // swizzled ds_read offsets (shorts)
  int offA[4], offB[8];
#pragma unroll
  for (int m = 0; m < 4; ++m) {
    int row = wr * 64 + m * 16 + lr;
    int li = row >> 1, sl = (row & 1) * 4 + kc;
    offA[m] = (li * 8 + (sl ^ (li & 7))) * 8;
  }
#pragma unroll
  for (int n = 0; n < 8; ++n) {
    int row = wc * 128 + n * 16 + lr;
    int li = row >> 1, sl = (row & 1) * 4 + kc;
    offB[n] = 4096 + (li * 8 + (sl ^ (li & 7))) * 8;
  }

  f32x4 acc[4][8] = {};

#define STAGE_B01(S, T) { stage16(srcB[0] + (T) * 32, &lds[S][lb[0]]); \
                          stage16(srcB[1] + (T) * 32, &lds[S][lb[1]]); }
#define STAGE_AB23(S, T) { stage16(srcA + (T) * 32, &lds[S][la]); \
                           stage16(srcB[2] + (T) * 32, &lds[S][lb[2]]); \
                           stage16(srcB[3] + (T) * 32, &lds[S][lb[3]]); }

#define KTILE(RB, SB, T2, VMS) { \
    short8 af[4]; \
    if ((T2) >= 0) STAGE_B01(SB, T2); \
    asm volatile("s_waitcnt vmcnt(" VMS ")" ::: "memory"); \
    __builtin_amdgcn_s_barrier(); \
    { short8 bf0[4]; \
      _Pragma("unroll") for (int m = 0; m < 4; ++m) \
        af[m] = *reinterpret_cast<const short8*>(&lds[RB][offA[m]]); \
      _Pragma("unroll") for (int n = 0; n < 4; ++n) \
        bf0[n] = *reinterpret_cast<const short8*>(&lds[RB][offB[n]]); \
      asm volatile("s_waitcnt lgkmcnt(0)"); \
      __builtin_amdgcn_s_setprio(1); \
      _Pragma("unroll") for (int m = 0; m < 4; ++m) \
        _Pragma("unroll") for (int n = 0; n < 4; ++n) \
          acc[m][n] = __builtin_amdgcn_mfma_f32_16x16x32_bf16(bf0[n], af[m], acc[m][n], 0, 0, 0); \
      __builtin_amdgcn_s_setprio(0); } \
    __builtin_amdgcn_s_barrier(); \
    if ((T2) >= 0) STAGE_AB23(SB, T2); \
    __builtin_amdgcn_s_barrier(); \
    { short8 bf1[4]; \
      _Pragma("unroll") for (int n = 0; n < 4; ++n) \
        bf1[n] = *reinterpret_cast<const short8*>(&lds[RB][offB[4 + n]]); \
      asm volatile("s_waitcnt lgkmcnt(0)"); \
      __builtin_amdgcn_s_setprio(1); \
      _Pragma("unroll") for (int m = 0; m < 4; ++m) \
        _Pragma("unroll") for (int n = 0; n < 4; ++n) \
          acc[m][4 + n] = __builtin_amdgcn_mfma_f32_16x16x32_bf16(bf1[n], af[m], acc[m][4 + n], 0, 0, 0); \
      __builtin_amdgcn_s_setprio(0); } \
    __builtin_amdgcn_s_barrier(); }

  // prologue: tiles 0,1 fully staged (10 loads in flight)
  STAGE_B01(0, 0); STAGE_AB23(0, 0);
  STAGE_B01(1, 1); STAGE_AB23(1, 1);

  for (int t = 0; t < 30; t += 3) {
    KTILE(0, 2, t + 2, "7")
    KTILE(1, 0, t + 3, "7")
    KTILE(2, 1, t + 4, "7")
  }
  KTILE(0, 0, -1, "5")   // tile 30
  KTILE(1, 1, -1, "0")   // tile 31

#undef KTILE
#undef STAGE_B01
#undef STAGE_AB23

  // epilogue: bias + relu, f32x4 stores (acc j-dim col-contiguous via operand swap)
#pragma unroll
  for (int n = 0; n < 8; ++n) {
    int col = bcol + wc * 128 + n * 16 + kc * 4;
    float4 bv = *reinterpret_cast<const float4*>(&bias[col]);
#pragma unroll
    for (int m = 0; m < 4; ++m) {
      int row = brow + wr * 64 + m * 16 + lr;
      f32x4 v = acc[m][n];
      float4 o;
      o.x = v[0] + bv.x; o.y = v[1] + bv.y; o.z = v[2] + bv.z; o.w = v[3] + bv.w;
      o.x = o.x > 0.f ? o.x : 0.f;
      o.y = o.y > 0.f ? o.y : 0.f;
      o.z = o.z > 0.f ? o.z : 0.f;
      o.w = o.w > 0.f ? o.w : 0.f;
      *reinterpret_cast<float4*>(&C[(size_t)row * 1024 + col]) = o;
    }
  }
}

extern "C" void kernel_launch(void* const* d_in, const int* in_sizes, int n_in,
                              void* d_out, int out_size, void* d_ws, size_t ws_size,
                              hipStream_t stream) {
  const float* x = (const float*)d_in[0];
  const float* filt = (const float*)d_in[1];
  const float* c0 = (const float*)d_in[2];
  const float* c1 = (const float*)d_in[3];
  const float* c2 = (const float*)d_in[4];
  const float* c3 = (const float*)d_in[5];
  const float* bias = (const float*)d_in[6];
  float* out = (float*)d_out;

  unsigned short* Tb = (unsigned short*)d_ws;        // 2 MB
  unsigned short* D = Tb + (size_t)1024 * 1024;      // 32 MB

  tt_prep<<<2304, 256, 0, stream>>>(x, filt, c0, c1, c2, c3, Tb, D);
  tt_gemm_n5<<<256, 512, 0, stream>>>(D, Tb, bias, out);
}

// Round 12
// 72.321 us; speedup vs baseline: 3.0572x; 1.0344x over previous
//
#include <hip/hip_runtime.h>
#include <hip/hip_bf16.h>
#include <stdint.h>

typedef __attribute__((ext_vector_type(8))) short short8;
typedef __attribute__((ext_vector_type(4))) float f32x4;

__device__ inline unsigned short f2bf(float f) {
  union { float f; unsigned u; } v; v.f = f;
  unsigned r = v.u + 0x7fffu + ((v.u >> 16) & 1u);
  return (unsigned short)(r >> 16);
}
__device__ inline float bf2f(unsigned short u) {
  union { unsigned u; float f; } v; v.u = ((unsigned)u) << 16; return v.f;
}

// -------- kernel 1: MERGED prep: blocks 0..255 build T (bf16), 256..2303 conv ----
__global__ __launch_bounds__(256) void tt_prep(
    const float* __restrict__ x, const float* __restrict__ filt,
    const float* __restrict__ c0, const float* __restrict__ c1,
    const float* __restrict__ c2, const float* __restrict__ c3,
    unsigned short* __restrict__ Tb, unsigned short* __restrict__ D) {
  __shared__ __align__(16) char smem[40960];
  const int tid = threadIdx.x;
  const int bid = blockIdx.x;

  if (bid < 256) {
    unsigned short* Lb = (unsigned short*)smem;
    unsigned short* Rb = (unsigned short*)(smem + 16384);
    for (int i = tid; i < 8192; i += 256) {
      int n1 = i & 7, n0 = (i >> 3) & 3, r2 = (i >> 5) & 7, m1 = (i >> 8) & 7, m0 = i >> 11;
      float s = 0.f;
#pragma unroll
      for (int r1 = 0; r1 < 8; ++r1)
        s += c0[(m0 * 8 + r1) * 4 + n0] * c1[(m1 * 8 + r2) * 64 + r1 * 8 + n1];
      Lb[i] = f2bf(s);
    }
    for (int i = tid; i < 8192; i += 256) {
      int n3 = i & 3, n2 = (i >> 2) & 7, m3 = (i >> 5) & 3, m2 = (i >> 7) & 7, r2 = i >> 10;
      float s = 0.f;
#pragma unroll
      for (int r3 = 0; r3 < 8; ++r3)
        s += c2[(m2 * 8 + r3) * 64 + r2 * 8 + n2] * c3[m3 * 32 + r3 * 4 + n3];
      Rb[i] = f2bf(s);
    }
    __syncthreads();
    int base = bid * 4096;
    for (int j = 0; j < 16; ++j) {
      int g = base + j * 256 + tid;
      int m = g >> 10, n = g & 1023;
      int m0 = m >> 8, m1 = (m >> 5) & 7, m2 = (m >> 2) & 7, m3 = m & 3;
      int n0 = n >> 8, n1 = (n >> 5) & 7, n2 = (n >> 2) & 7, n3 = n & 3;
      float s = 0.f;
#pragma unroll
      for (int r2 = 0; r2 < 8; ++r2)
        s += bf2f(Lb[(((m0 * 8 + m1) * 8 + r2) * 4 + n0) * 8 + n1]) *
             bf2f(Rb[(((r2 * 8 + m2) * 4 + m3) * 8 + n2) * 4 + n3]);
      Tb[(size_t)m * 1024 + n] = f2bf(s);
    }
    return;
  }

  float (*xs)[32][32] = (float(*)[32][32])smem;
  int cb = bid - 256;
  int cg = cb & 31, strip = (cb >> 5) & 3, b = cb >> 7;
  int h0 = strip * 8;
  float4 z4; z4.x = z4.y = z4.z = z4.w = 0.f;
#pragma unroll
  for (int i = 0; i < 10; ++i) {
    int j = tid + 256 * i;
    int row = j >> 8, w = (j >> 3) & 31, c4 = j & 7;
    int gh = h0 - 1 + row;
    float4 v = z4;
    if ((unsigned)gh < 32u)
      v = *reinterpret_cast<const float4*>(x + ((size_t)((b * 32 + gh) * 32 + w)) * 1024 + cg * 32 + c4 * 4);
    *reinterpret_cast<float4*>(&xs[row][w][c4 * 4]) = v;
  }
  float F[9];
#pragma unroll
  for (int i = 0; i < 9; ++i) F[i] = filt[i];
  __syncthreads();

  int c4 = tid & 7, w = tid >> 3;
#define LD3(r, d0, d1, d2) { \
    d1 = *reinterpret_cast<const float4*>(&xs[r][w][c4 * 4]); \
    d0 = (w > 0)  ? *reinterpret_cast<const float4*>(&xs[r][w - 1][c4 * 4]) : z4; \
    d2 = (w < 31) ? *reinterpret_cast<const float4*>(&xs[r][w + 1][c4 * 4]) : z4; }
#define ACC4(a, f, v) { a.x += (f) * v.x; a.y += (f) * v.y; a.z += (f) * v.z; a.w += (f) * v.w; }
  float4 a00, a01, a02, a10, a11, a12, a20, a21, a22;
  LD3(0, a00, a01, a02);
  LD3(1, a10, a11, a12);
#pragma unroll
  for (int h = 0; h < 8; ++h) {
    LD3(h + 2, a20, a21, a22);
    float4 s = z4;
    ACC4(s, F[0], a00); ACC4(s, F[1], a01); ACC4(s, F[2], a02);
    ACC4(s, F[3], a10); ACC4(s, F[4], a11); ACC4(s, F[5], a12);
    ACC4(s, F[6], a20); ACC4(s, F[7], a21); ACC4(s, F[8], a22);
    ushort4 o;
    o.x = f2bf(s.x); o.y = f2bf(s.y); o.z = f2bf(s.z); o.w = f2bf(s.w);
    *reinterpret_cast<ushort4*>(&D[((size_t)(b * 1024 + (h0 + h) * 32 + w)) * 1024 + cg * 32 + c4 * 4]) = o;
    a00 = a10; a01 = a11; a02 = a12;
    a10 = a20; a11 = a21; a12 = a22;
  }
#undef LD3
#undef ACC4
}

// -------- kernel 2: 256x256 GEMM, BK=32, ring-4 LDS, REGISTER-double-buffered frags ----
// C[p,m] = relu( sum_k D[p,k]*Tb[m,k] + bias[m] ), M=16384, N=1024, K=1024.
// Iter t: lgkmcnt(12) [reads(t-1) retired; reads(t)=12 newest may fly]
//         vmcnt(4)    [my chunks of slot t+1 done; t+2's 4 in flight]
//         barrier     [globally: slot t+1 resident AND all waves' reads(t-1) done]
//         STAGE(t+3 -> slot (t+3)%4 = (t-1)%4)  [safe per the barrier above]
//         issue 12 ds_reads(t+1) -> NEXT frag set [no wait]
//         MFMA(t) from CURRENT frag set [operands already resident]
// => LDS pipe (reads t+1 + DMA writes t+3) streams UNDER MFMA(t).
// Swizzle: row-pair 128B lines, slot' = slot ^ (line&7); pre-swizzled GLOBAL
// source, linear LDS dest. Even/odd unroll keeps frag sets statically indexed.
__device__ inline void stage16(const unsigned short* g, unsigned short* l) {
  __builtin_amdgcn_global_load_lds(
      (const __attribute__((address_space(1))) void*)g,
      (__attribute__((address_space(3))) void*)l, 16, 0, 0);
}

__global__ __launch_bounds__(512, 2) void tt_gemm_rb(
    const unsigned short* __restrict__ A,   // [16384, 1024] bf16
    const unsigned short* __restrict__ Bt,  // [1024, 1024] bf16
    const float* __restrict__ bias,
    float* __restrict__ C) {
  __shared__ unsigned short lds[4][16384];  // [ring][A:0..8192 | B:8192..16384], 128 KiB
  const int tid = threadIdx.x;
  const int lane = tid & 63, wave = tid >> 6;
  const int wr = wave >> 2, wc = wave & 3;      // 2M x 4N waves; per-wave 128x64
  const int lr = lane & 15, kc = lane >> 4;

  // XCD-bijective swizzle (256 blocks, 8 XCDs)
  int lin = blockIdx.x + blockIdx.y * 64;
  int Lg = ((lin & 7) << 5) | (lin >> 3);
  int brow = (Lg & 63) * 256;
  int bcol = (Lg >> 6) * 256;

  // staging: per op-tile 1024 x 16B chunks; thread stages q0=tid, q1=tid+512 of each
  int row0, k0, row1, k1;
  { int q = tid;       int li = q >> 3, c = (q & 7) ^ (li & 7); row0 = 2 * li + (c >> 2); k0 = (c & 3) * 8; }
  { int q = tid + 512; int li = q >> 3, c = (q & 7) ^ (li & 7); row1 = 2 * li + (c >> 2); k1 = (c & 3) * 8; }
  const unsigned short* pa0 = A + (size_t)(brow + row0) * 1024 + k0;
  const unsigned short* pa1 = A + (size_t)(brow + row1) * 1024 + k1;
  const unsigned short* pb0 = Bt + (size_t)(bcol + row0) * 1024 + k0;
  const unsigned short* pb1 = Bt + (size_t)(bcol + row1) * 1024 + k1;
  const int la0 = tid * 8, la1 = (tid + 512) * 8;

  // swizzled ds_read offsets (shorts)
  int offA[8], offB[4];
#pragma unroll
  for (int m = 0; m < 8; ++m) {
    int row = wr * 128 + m * 16 + lr;
    int li = row >> 1, sl = (row & 1) * 4 + kc;
    offA[m] = (li * 8 + (sl ^ (li & 7))) * 8;
  }
#pragma unroll
  for (int n = 0; n < 4; ++n) {
    int row = wc * 64 + n * 16 + lr;
    int li = row >> 1, sl = (row & 1) * 4 + kc;
    offB[n] = 8192 + (li * 8 + (sl ^ (li & 7))) * 8;
  }

  f32x4 acc[8][4] = {};
  short8 a0[8], b0[4], a1[8], b1[4];   // two fragment sets (reg dbuf)

#define STAGE(S, T) { \
    stage16(pa0 + (T) * 32, &lds[S][la0]); \
    stage16(pa1 + (T) * 32, &lds[S][la1]); \
    stage16(pb0 + (T) * 32, &lds[S][8192 + la0]); \
    stage16(pb1 + (T) * 32, &lds[S][8192 + la1]); }

#define READF(AF, BF, S) { \
    _Pragma("unroll") for (int m = 0; m < 8; ++m) \
      AF[m] = *reinterpret_cast<const short8*>(&lds[S][offA[m]]); \
    _Pragma("unroll") for (int n = 0; n < 4; ++n) \
      BF[n] = *reinterpret_cast<const short8*>(&lds[S][offB[n]]); }

#define MFMAS(AF, BF) { \
    _Pragma("unroll") for (int m = 0; m < 8; ++m) \
      _Pragma("unroll") for (int n = 0; n < 4; ++n) \
        acc[m][n] = __builtin_amdgcn_mfma_f32_16x16x32_bf16(BF[n], AF[m], acc[m][n], 0, 0, 0); }

  // ITER: see header comment. AFc/BFc = current set (tile T); AFn/BFn = next.
#define ITER(T, AFc, BFc, AFn, BFn, DOSTAGE, VMS) { \
    asm volatile("s_waitcnt lgkmcnt(12)" ::: "memory"); \
    asm volatile("s_waitcnt vmcnt(" VMS ")" ::: "memory"); \
    __builtin_amdgcn_s_barrier(); \
    if (DOSTAGE) STAGE(((T) + 3) & 3, (T) + 3); \
    READF(AFn, BFn, ((T) + 1) & 3); \
    MFMAS(AFc, BFc); }

  // prologue: tiles 0..2 staged (12 loads); tile0 resident after vmcnt(8)+barrier.
  STAGE(0, 0); STAGE(1, 1); STAGE(2, 2);
  asm volatile("s_waitcnt vmcnt(8)" ::: "memory");
  __builtin_amdgcn_s_barrier();
  READF(a0, b0, 0);

  for (int tp = 0; tp < 14; ++tp) {
    int t = 2 * tp;
    ITER(t,     a0, b0, a1, b1, 1, "4")
    ITER(t + 1, a1, b1, a0, b0, 1, "4")
  }
  // t=28 (stage 31), 29, 30, 31 peeled
  ITER(28, a0, b0, a1, b1, 1, "4")
  ITER(29, a1, b1, a0, b0, 0, "4")
  ITER(30, a0, b0, a1, b1, 0, "0")
  // t=31: no reads, no stage; compiler inserts lgkm waits for a1/b1.
  MFMAS(a1, b1);

#undef ITER
#undef MFMAS
#undef READF
#undef STAGE

  // epilogue: bias + relu, f32x4 stores (acc j-dim col-contiguous via operand swap)
#pragma unroll
  for (int n = 0; n < 4; ++n) {
    int col = bcol + wc * 64 + n * 16 + kc * 4;
    float4 bv = *reinterpret_cast<const float4*>(&bias[col]);
#pragma unroll
    for (int m = 0; m < 8; ++m) {
      int row = brow + wr * 128 + m * 16 + lr;
      f32x4 v = acc[m][n];
      float4 o;
      o.x = v[0] + bv.x; o.y = v[1] + bv.y; o.z = v[2] + bv.z; o.w = v[3] + bv.w;
      o.x = o.x > 0.f ? o.x : 0.f;
      o.y = o.y > 0.f ? o.y : 0.f;
      o.z = o.z > 0.f ? o.z : 0.f;
      o.w = o.w > 0.f ? o.w : 0.f;
      *reinterpret_cast<float4*>(&C[(size_t)row * 1024 + col]) = o;
    }
  }
}

extern "C" void kernel_launch(void* const* d_in, const int* in_sizes, int n_in,
                              void* d_out, int out_size, void* d_ws, size_t ws_size,
                              hipStream_t stream) {
  const float* x = (const float*)d_in[0];
  const float* filt = (const float*)d_in[1];
  const float* c0 = (const float*)d_in[2];
  const float* c1 = (const float*)d_in[3];
  const float* c2 = (const float*)d_in[4];
  const float* c3 = (const float*)d_in[5];
  const float* bias = (const float*)d_in[6];
  float* out = (float*)d_out;

  unsigned short* Tb = (unsigned short*)d_ws;        // 2 MB
  unsigned short* D = Tb + (size_t)1024 * 1024;      // 32 MB

  tt_prep<<<2304, 256, 0, stream>>>(x, filt, c0, c1, c2, c3, Tb, D);
  dim3 grid(64, 4);
  tt_gemm_rb<<<grid, 512, 0, stream>>>(D, Tb, bias, out);
}